// Round 1
// baseline (5351.547 us; speedup 1.0000x reference)
//
#include <hip/hip_runtime.h>
#include <hip/hip_bf16.h>
#include <math.h>

// Problem constants
#define BSZ 64
#define TT  512
#define DD  512
#define UU  512
#define NZ  2048   // 4*U

#define NSL    32    // u-slices (workers per batch group)
#define USL    16    // units per slice
#define NBG    4     // batch groups
#define BG     16    // batches per group (= MFMA m)
#define KSTEPS 16    // 512 / 32 (MFMA k=32)

using short8  = __attribute__((ext_vector_type(8))) short;
using floatx4 = __attribute__((ext_vector_type(4))) float;
typedef unsigned long long u64;

// ---------------------------------------------------------------------------
// Phase 1: zx = x @ Wk.  M=32768, K=512, N=2048. fp32 tiled GEMM (unchanged).
// ---------------------------------------------------------------------------
template <bool ZXBF16>
__global__ __launch_bounds__(256) void gemm_zx(const float* __restrict__ A,
                                               const float* __restrict__ B,
                                               void* __restrict__ Cout) {
  __shared__ float As[16][65];
  __shared__ float Bs[16][64];

  const int tid = threadIdx.x;
  const int tx = tid & 15;
  const int ty = tid >> 4;
  const int m0 = blockIdx.y * 64;
  const int n0 = blockIdx.x * 64;

  const int lm  = tid >> 2;
  const int lk4 = (tid & 3) * 4;
  const int lk  = tid >> 4;
  const int ln4 = (tid & 15) * 4;

  float acc[4][4] = {};

  for (int k0 = 0; k0 < DD; k0 += 16) {
    float4 av = *(const float4*)(A + (size_t)(m0 + lm) * DD + k0 + lk4);
    float4 bv = *(const float4*)(B + (size_t)(k0 + lk) * NZ + n0 + ln4);
    As[lk4 + 0][lm] = av.x;
    As[lk4 + 1][lm] = av.y;
    As[lk4 + 2][lm] = av.z;
    As[lk4 + 3][lm] = av.w;
    *(float4*)&Bs[lk][ln4] = bv;
    __syncthreads();
#pragma unroll
    for (int kk = 0; kk < 16; ++kk) {
      float a[4], b[4];
#pragma unroll
      for (int i = 0; i < 4; ++i) a[i] = As[kk][ty * 4 + i];
#pragma unroll
      for (int j = 0; j < 4; ++j) b[j] = Bs[kk][tx * 4 + j];
#pragma unroll
      for (int i = 0; i < 4; ++i)
#pragma unroll
        for (int j = 0; j < 4; ++j) acc[i][j] = fmaf(a[i], b[j], acc[i][j]);
    }
    __syncthreads();
  }

#pragma unroll
  for (int i = 0; i < 4; ++i) {
    const size_t row = (size_t)(m0 + ty * 4 + i) * NZ + n0 + tx * 4;
    if constexpr (ZXBF16) {
      __hip_bfloat16* C = (__hip_bfloat16*)Cout;
#pragma unroll
      for (int j = 0; j < 4; ++j) C[row + j] = __float2bfloat16(acc[i][j]);
    } else {
      float* C = (float*)Cout;
      *(float4*)&C[row] = make_float4(acc[i][0], acc[i][1], acc[i][2], acc[i][3]);
    }
  }
}

// ---------------------------------------------------------------------------
// Phase 2: ONE persistent kernel, XCD-CLUSTERED.
//
// Launch 256 blocks x 256 threads. 132 KiB LDS forces exactly 1 block/CU, so
// all 256 blocks are co-resident and each XCD hosts exactly its 32 CUs' worth
// of blocks. Blocks self-assign roles at runtime: xcd = s_getreg(XCC_ID);
// XCD k (k<4) owns batch group k, slot = per-XCD atomicAdd arrival index
// (0..31) = u-slice. XCDs 4..7 exit immediately.
//
// Consequence: ALL h traffic for a bg's recurrence chain stays inside ONE
// XCD's L2 (the shared coherence point for its 32 CUs). h stores are now
// PLAIN stores (land in the local L2, drained by the vmcnt(0) implied by the
// post-epilogue __syncthreads before tid0 publishes the flag). h loads are
// plain b128 loads: the reader's L2 IS the producer's L2, and each h address
// (plane t+1) is written exactly once and never read or cached by anyone
// before its producer's flag publishes, so no stale copy can exist in any
// L1/L2 on the path. Flags keep the proven agent-scope atomic store/load
// protocol (one IF$ hop per step — the only remaining fabric crossing).
//
// Deadlock safety: 256 blocks, 256 CUs, 1 block/CU => every CU gets exactly
// one block at dispatch; the first (and only) 32 arrivals per XCD become that
// XCD's 32 workers, all resident. Non-workers exit without touching flags.
// ---------------------------------------------------------------------------
__device__ __forceinline__ floatx4 mfma16(short8 a, short8 b, floatx4 c) {
  return __builtin_amdgcn_mfma_f32_16x16x32_bf16(a, b, c, 0, 0, 0);
}

template <bool ZXBF16>
__global__ __launch_bounds__(256) void lstm_persist(
    const void* __restrict__ zx_, const float* __restrict__ Wr,
    const float* __restrict__ bias, unsigned short* __restrict__ h_hi,
    unsigned short* __restrict__ h_lo, int* __restrict__ flags,
    int* __restrict__ xcd_ctr, float* __restrict__ out) {
  __shared__ int s_role[2];
  extern __shared__ char lds[];
  unsigned short* wr_hi = (unsigned short*)lds;            // [K][g][lane][8]
  unsigned short* wr_lo = wr_hi + KSTEPS * 4 * 64 * 8;     // 32768 ushorts each
  float* z_ex = (float*)(wr_lo + KSTEPS * 4 * 64 * 8);     // [4 g][16 b][16 u]

  const int tid = threadIdx.x;

  // ---- runtime role assignment: cluster by physical XCD ----
  if (tid == 0) {
    unsigned x;
    asm volatile("s_getreg_b32 %0, hwreg(HW_REG_XCC_ID)" : "=s"(x));
    const int xcd = (int)(x & 7u);
    int slot = NSL;  // default: non-worker
    if (xcd < NBG) slot = atomicAdd(&xcd_ctr[xcd * 16], 1);
    s_role[0] = xcd;
    s_role[1] = slot;
  }
  __syncthreads();
  const int bg = s_role[0];           // batch group = XCD id
  const int sl = s_role[1];           // u-slice = arrival slot on this XCD
  if (bg >= NBG || sl >= NSL) return; // XCDs 4..7 (and any overflow) idle

  const int g = tid >> 6;             // wave = gate 0..3
  const int lane = tid & 63;
  const int u0 = sl * USL;

  // ---- one-time: preformat Wr slice into LDS (split bf16, B-frag order) ----
  {
    const int cidx = tid & 63;        // gg*16+u within slice
    const int koff = tid >> 6;        // 0..3
    const int gg = cidx >> 4, u = cidx & 15;
    const int col = gg * UU + u0 + u;
    for (int k0 = 0; k0 < DD; k0 += 4) {
      const int k = k0 + koff;
      const float v = Wr[(size_t)k * NZ + col];
      const __hip_bfloat16 vh = __float2bfloat16(v);
      const float rem = v - __bfloat162float(vh);
      const __hip_bfloat16 vl = __float2bfloat16(rem);
      const int K = k >> 5, kg = (k >> 3) & 3, j = k & 7;
      const int off = ((K * 4 + gg) * 64 + (kg * 16 + u)) * 8 + j;
      wr_hi[off] = *(const unsigned short*)&vh;
      wr_lo[off] = *(const unsigned short*)&vl;
    }
  }
  __syncthreads();

  // MFMA A-fragment addressing: m = bg*16 + (lane&15), kgroup = lane>>4
  const int am = lane & 15, akg = lane >> 4;
  const size_t arow = (size_t)(bg * BG + am) * UU + akg * 8;  // ushort idx

  // epilogue mapping: thread -> (local batch eb, unit eu)
  const int eb = tid >> 4;            // 0..15
  const int eu = tid & 15;            // 0..15
  const int b = bg * BG + eb;         // global batch
  const float bias_i = bias[0 * UU + u0 + eu];
  const float bias_f = bias[1 * UU + u0 + eu];
  const float bias_g = bias[2 * UU + u0 + eu];
  const float bias_o = bias[3 * UU + u0 + eu];
  float c_state = 0.f;
  const size_t plane_t = (size_t)BSZ * UU;          // 32768 ushorts / timestep
  // packed-pair word index for (b, eu even): (b*UU + u0 + eu)/2
  const int wword = (b * UU + u0 + eu) >> 1;

  int* myflag = flags + (bg * NSL + sl) * 16;

  for (int t = 0; t < TT; ++t) {
    // ---- zx prefetch for this step (independent of h_t) ----
    float zi, zf, zg, zo;
    {
      const size_t zb = ((size_t)b * TT + t) * NZ + u0 + eu;
      if constexpr (ZXBF16) {
        const unsigned short* zx = (const unsigned short*)zx_;
        zi = __bfloat162float(*(const __hip_bfloat16*)&zx[zb + 0 * UU]);
        zf = __bfloat162float(*(const __hip_bfloat16*)&zx[zb + 1 * UU]);
        zg = __bfloat162float(*(const __hip_bfloat16*)&zx[zb + 2 * UU]);
        zo = __bfloat162float(*(const __hip_bfloat16*)&zx[zb + 3 * UU]);
      } else {
        const float* zx = (const float*)zx_;
        zi = zx[zb + 0 * UU];
        zf = zx[zb + 1 * UU];
        zg = zx[zb + 2 * UU];
        zo = zx[zb + 3 * UU];
      }
    }

    // ---- acquire h_t: relaxed poll of this bg's 32 flags, then wg fence ----
    if (tid < NSL) {
      const int* fp = flags + (bg * NSL + tid) * 16;
      while (__hip_atomic_load(fp, __ATOMIC_RELAXED, __HIP_MEMORY_SCOPE_AGENT) < t) {
      }
    }
    __syncthreads();
    __builtin_amdgcn_fence(__ATOMIC_ACQUIRE, "workgroup");

    // ---- z[16b][16u] for gate g via split-bf16 MFMA (h from local L2) ----
    const unsigned short* Ahi = h_hi + (size_t)t * plane_t + arow;
    const unsigned short* Alo = h_lo + (size_t)t * plane_t + arow;
    floatx4 a0 = {0, 0, 0, 0}, a1 = {0, 0, 0, 0}, a2 = {0, 0, 0, 0};
#pragma unroll 4
    for (int K = 0; K < KSTEPS; ++K) {
      const short8 ahi = *(const short8*)(Ahi + K * 32);
      const short8 alo = *(const short8*)(Alo + K * 32);
      const short8 bhi = *(const short8*)(wr_hi + ((K * 4 + g) * 64 + lane) * 8);
      const short8 blo = *(const short8*)(wr_lo + ((K * 4 + g) * 64 + lane) * 8);
      a0 = mfma16(ahi, bhi, a0);
      a1 = mfma16(ahi, blo, a1);
      a2 = mfma16(alo, bhi, a2);
    }
    // C layout: u = lane&15, b-in-tile = (lane>>4)*4 + r
#pragma unroll
    for (int r = 0; r < 4; ++r) {
      const int bb = (lane >> 4) * 4 + r;
      z_ex[(g * 16 + bb) * 16 + (lane & 15)] = a0[r] + a1[r] + a2[r];
    }
    __syncthreads();

    // ---- pointwise gates: thread = (eb, eu) ----
    zi += z_ex[(0 * 16 + eb) * 16 + eu] + bias_i;
    zf += z_ex[(1 * 16 + eb) * 16 + eu] + bias_f;
    zg += z_ex[(2 * 16 + eb) * 16 + eu] + bias_g;
    zo += z_ex[(3 * 16 + eb) * 16 + eu] + bias_o;

    const float ig = 1.f / (1.f + expf(-zi));
    const float fg = 1.f / (1.f + expf(-zf));
    const float gg = tanhf(zg);
    const float og = 1.f / (1.f + expf(-zo));
    c_state = fg * c_state + ig * gg;
    const float hn = og * tanhf(c_state);

    // split-bf16; pack pair-words via shfl, even threads store PLAIN 32-bit
    // words (same-XCD consumers; shared L2 is the coherence point).
    const __hip_bfloat16 hh = __float2bfloat16(hn);
    const float hrem = hn - __bfloat162float(hh);
    const __hip_bfloat16 hl = __float2bfloat16(hrem);
    const unsigned int vhi = (unsigned int)*(const unsigned short*)&hh;
    const unsigned int vlo = (unsigned int)*(const unsigned short*)&hl;
    const unsigned int phi_n = (unsigned int)__shfl_xor((int)vhi, 1);
    const unsigned int plo_n = (unsigned int)__shfl_xor((int)vlo, 1);
    if ((tid & 1) == 0) {
      const unsigned int whi = vhi | (phi_n << 16);
      const unsigned int wlo = vlo | (plo_n << 16);
      unsigned int* phi = (unsigned int*)(h_hi + (size_t)(t + 1) * plane_t) + wword;
      unsigned int* plo = (unsigned int*)(h_lo + (size_t)(t + 1) * plane_t) + wword;
      *phi = whi;
      *plo = wlo;
    }

    if (t == TT - 1) out[(size_t)b * UU + u0 + eu] = hn;

    // ---- release: barrier drains vmcnt (stores visible in local L2) ----
    __syncthreads();
    if (tid == 0)
      __hip_atomic_store(myflag, t + 1, __ATOMIC_RELAXED,
                         __HIP_MEMORY_SCOPE_AGENT);
  }
}

// ---------------------------------------------------------------------------
extern "C" void kernel_launch(void* const* d_in, const int* in_sizes, int n_in,
                              void* d_out, int out_size, void* d_ws, size_t ws_size,
                              hipStream_t stream) {
  const float* x    = (const float*)d_in[0];
  const float* Wk   = (const float*)d_in[1];
  const float* Wr   = (const float*)d_in[2];
  const float* bias = (const float*)d_in[3];
  float* out = (float*)d_out;

  const size_t plane_t = (size_t)BSZ * UU;                      // 32768
  const size_t hplane_bytes = (size_t)(TT + 1) * plane_t * 2;   // 32.06 MiB
  const size_t flags_bytes = (size_t)NBG * NSL * 16 * 4;        // 8 KiB
  const size_t ctr_bytes = (size_t)8 * 16 * 4;                  // 512 B
  const size_t zx_f32_bytes = (size_t)BSZ * TT * NZ * 4;        // 256 MiB

  const size_t need_f32 = zx_f32_bytes + 2 * hplane_bytes + flags_bytes + ctr_bytes;
  const bool use_bf16_zx = (ws_size < need_f32);
  const size_t zx_bytes = use_bf16_zx ? zx_f32_bytes / 2 : zx_f32_bytes;

  char* ws = (char*)d_ws;
  void* zx = (void*)ws;
  unsigned short* h_hi = (unsigned short*)(ws + zx_bytes);
  unsigned short* h_lo = (unsigned short*)(ws + zx_bytes + hplane_bytes);
  int* flags = (int*)(ws + zx_bytes + 2 * hplane_bytes);
  int* xcd_ctr = (int*)(ws + zx_bytes + 2 * hplane_bytes + flags_bytes);

  hipMemsetAsync(h_hi, 0, plane_t * 2, stream);  // h_0 slab
  hipMemsetAsync(h_lo, 0, plane_t * 2, stream);
  hipMemsetAsync(flags, 0, flags_bytes + ctr_bytes, stream);

  dim3 ggrid(NZ / 64, (BSZ * TT) / 64);
  if (use_bf16_zx)
    gemm_zx<true><<<ggrid, 256, 0, stream>>>(x, Wk, zx);
  else
    gemm_zx<false><<<ggrid, 256, 0, stream>>>(x, Wk, zx);

  const int lds_bytes = KSTEPS * 4 * 64 * 8 * 2 * 2 + 4 * 16 * 16 * 4;  // 135168
  dim3 pgrid(256);  // 1 block/CU (LDS-limited) => exactly 32 blocks per XCD
  if (use_bf16_zx) {
    hipFuncSetAttribute(reinterpret_cast<const void*>(lstm_persist<true>),
                        hipFuncAttributeMaxDynamicSharedMemorySize, lds_bytes);
    lstm_persist<true><<<pgrid, 256, lds_bytes, stream>>>(zx, Wr, bias, h_hi, h_lo,
                                                          flags, xcd_ctr, out);
  } else {
    hipFuncSetAttribute(reinterpret_cast<const void*>(lstm_persist<false>),
                        hipFuncAttributeMaxDynamicSharedMemorySize, lds_bytes);
    lstm_persist<false><<<pgrid, 256, lds_bytes, stream>>>(zx, Wr, bias, h_hi, h_lo,
                                                           flags, xcd_ctr, out);
  }
}